// Round 3
// baseline (55329.022 us; speedup 1.0000x reference)
//
#include <hip/hip_runtime.h>

#define NBLK 256
#define NTHR 512
#define HDIM 512
#define TSTEPS 1024
#define WUP 512
#define WPL 786432   /* weight plane elems: 1536*512 */
#define HPL 524288   /* h plane elems per buffer: 1024*512 */
#define PAR 65536    /* LDS parity stride */

typedef unsigned short u16;
typedef unsigned int u32;
typedef __bf16 bf16x8 __attribute__((ext_vector_type(8)));
typedef float f32x4 __attribute__((ext_vector_type(4)));

typedef __attribute__((address_space(3))) void as3v;
typedef __attribute__((address_space(1))) const void as1cv;

__device__ __forceinline__ void gload16(const u16* g, char* l) {
  __builtin_amdgcn_global_load_lds((as1cv*)g, (as3v*)l, 16, 0, 0);
}

__device__ __forceinline__ u16 f2bf(float f) {
  u32 u = __float_as_uint(f);
  u += 0x7fffu + ((u >> 16) & 1u);
  return (u16)(u >> 16);
}
__device__ __forceinline__ float bf2f(u16 s) {
  return __uint_as_float(((u32)s) << 16);
}
__device__ __forceinline__ float sigm(float v) { return 1.f / (1.f + __expf(-v)); }
__device__ __forceinline__ float tanh_(float v) {
  float e = __expf(2.f * v);
  return 1.f - 2.f / (e + 1.f);
}
__device__ __forceinline__ f32x4 MFMA(bf16x8 a, bf16x8 b, f32x4 c) {
  return __builtin_amdgcn_mfma_f32_16x16x32_bf16(a, b, c, 0, 0, 0);
}

// ---- global 2-level barrier (init only) ----
__device__ __forceinline__ void gbar_arrive(int* bar, int target) {
  __syncthreads();
  if (threadIdx.x == 0) {
    __threadfence();
    int g = (int)(blockIdx.x >> 4);
    if (__hip_atomic_fetch_add(&bar[g * 32], 1, __ATOMIC_ACQ_REL, __HIP_MEMORY_SCOPE_AGENT) == 15) {
      __hip_atomic_store(&bar[g * 32], 0, __ATOMIC_RELAXED, __HIP_MEMORY_SCOPE_AGENT);
      if (__hip_atomic_fetch_add(&bar[512], 1, __ATOMIC_ACQ_REL, __HIP_MEMORY_SCOPE_AGENT) == 15) {
        __hip_atomic_store(&bar[512], 0, __ATOMIC_RELAXED, __HIP_MEMORY_SCOPE_AGENT);
        __hip_atomic_store(&bar[516], target, __ATOMIC_RELEASE, __HIP_MEMORY_SCOPE_AGENT);
      }
    }
  }
}
__device__ __forceinline__ void gbar_wait(int* bar, int target) {
  if (threadIdx.x == 0) {
    while (__hip_atomic_load(&bar[516], __ATOMIC_ACQUIRE, __HIP_MEMORY_SCOPE_AGENT) < target)
      __builtin_amdgcn_s_sleep(2);
  }
  __syncthreads();
}

// ---- per-rb-group barrier (16 blocks): gb[0]=ctr, gb[16]=gen ----
__device__ __forceinline__ void g_arrive(int* gb, int target) {
  __syncthreads();
  if (threadIdx.x == 0) {
    __threadfence();
    if (__hip_atomic_fetch_add(gb, 1, __ATOMIC_ACQ_REL, __HIP_MEMORY_SCOPE_AGENT) == 15) {
      __hip_atomic_store(gb, 0, __ATOMIC_RELAXED, __HIP_MEMORY_SCOPE_AGENT);
      __hip_atomic_store(gb + 16, target, __ATOMIC_RELEASE, __HIP_MEMORY_SCOPE_AGENT);
    }
  }
}
__device__ __forceinline__ void g_wait(int* gb, int target) {
  if (threadIdx.x == 0) {
    while (__hip_atomic_load(gb + 16, __ATOMIC_ACQUIRE, __HIP_MEMORY_SCOPE_AGENT) < target)
      __builtin_amdgcn_s_sleep(2);
  }
  __syncthreads();
}

__global__ __launch_bounds__(NTHR, 2) void gru_seq_kernel(
    const float* __restrict__ input, const float* __restrict__ Wih1,
    const float* __restrict__ Whh1, const float* __restrict__ bih1, const float* __restrict__ bhh1,
    const float* __restrict__ Wih2, const float* __restrict__ Whh2,
    const float* __restrict__ bih2, const float* __restrict__ bhh2,
    const float* __restrict__ Wlin, const float* __restrict__ blinp,
    float* __restrict__ dout, u16* __restrict__ wsp, float* __restrict__ outsc,
    int* __restrict__ bar) {
  __shared__ __align__(16) char smem[131072];
  const int wg = blockIdx.x, tid = threadIdx.x;
  const int lane = tid & 63, wv = tid >> 6;
  const int l15 = lane & 15, l4 = lane >> 4;
  const int rt = wv >> 1, ch = wv & 1;

  u16* Wh1h = wsp;           u16* Wh1l = wsp + WPL;
  u16* Wi2h = wsp + 2 * WPL; u16* Wi2l = wsp + 3 * WPL;
  u16* Wh2h = wsp + 4 * WPL; u16* Wh2l = wsp + 5 * WPL;
  u16* hb_  = wsp + 6 * WPL;
  u16* h1h = hb_;            u16* h1l = hb_ + 2 * HPL;   // [2][HPL] each
  u16* h2h = hb_ + 4 * HPL;  u16* h2l = hb_ + 6 * HPL;

  // ---- init: split weights into bf16 hi/lo planes ----
  for (int i = wg * NTHR + tid; i < 3 * WPL; i += NBLK * NTHR) {
    int m = i / WPL, r = i - m * WPL;
    const float* src = (m == 0) ? Whh1 : (m == 1) ? Wih2 : Whh2;
    u16* dh = (m == 0) ? Wh1h : (m == 1) ? Wi2h : Wh2h;
    u16* dl = (m == 0) ? Wh1l : (m == 1) ? Wi2l : Wh2l;
    float v = src[r];
    u16 hbv = f2bf(v);
    dh[r] = hbv; dl[r] = f2bf(v - bf2f(hbv));
  }
  gbar_arrive(bar + 1024, 1);

  // ---- block decomposition (XCD-bijective): xcd = wg&7 ----
  const int xm = wg >> 3;
  const int cb = (wg & 7) * 2 + (xm & 1);   // 0..15 column-block (32 hcols)
  const int rb = xm >> 1;                   // 0..15 row-block (64 batch rows)
  int* gb1 = bar + rb * 64;
  int* gb2 = bar + rb * 64 + 32;

  // ---- per-lane constants ----
  const int j = cb * 32 + ch * 16 + l15;
  const float blin = blinp[0];
  const float wi_r = Wih1[j], wi_z = Wih1[j + 512], wi_n = Wih1[j + 1024];
  const float bi_r = bih1[j], bi_z = bih1[j + 512], bi_n = bih1[j + 1024];
  const float bh_r = bhh1[j], bh_z = bhh1[j + 512], bh_n = bhh1[j + 1024];
  const float c2i_r = bih2[j], c2i_z = bih2[j + 512], c2i_n = bih2[j + 1024];
  const float c2h_r = bhh2[j], c2h_z = bhh2[j + 512], c2h_n = bhh2[j + 1024];
  const float wlj = Wlin[j];

  // ---- staging slot precompute: G_A (8 slots/wave, 64KB chunk) ----
  // chunk layout: Ah@0(8K) Al@8192 Bh@16384(24K: Wih2 rows0-95, Whh1 rows96-191) Bl@40960(24K)
  const u16* saptr[8]; u32 safl[8];
#pragma unroll
  for (int i = 0; i < 8; ++i) {
    int q = wv * 8 + i;
    int off = q * 1024 + lane * 16;
    const u16* base; u32 eoff; u32 fl = 0;
    if (q < 16) {
      int loc = off & 8191;
      int row = loc >> 7, bir = loc & 127;
      int lb = bir ^ ((row & 7) << 4);
      eoff = (u32)(rb * 64 + row) * HDIM + (u32)(lb >> 1);
      base = (q < 8) ? h1h : h1l;
      fl = 1;
    } else {
      int loc = off - 16384;
      int lo = 0; if (loc >= 24576) { lo = 1; loc -= 24576; }
      int brow = loc >> 7, bir = loc & 127;
      int lb = bir ^ ((brow & 7) << 4);
      int mat = (brow >= 96) ? 1 : 0;
      int s = brow - 96 * mat;
      int g = s >> 5, r = s & 31;
      eoff = (u32)(g * 512 + cb * 32 + r) * HDIM + (u32)(lb >> 1);
      base = mat ? (lo ? Wh1l : Wh1h) : (lo ? Wi2l : Wi2h);
    }
    saptr[i] = base + eoff; safl[i] = fl;
  }
  // ---- staging slots: G_H (5 slots/wave, 40KB chunk) ----
  // layout: Ah@0 Al@8192 Bh@16384(12K: Whh2) Bl@28672(12K)
  const u16* shptr[5]; u32 shfl_[5];
#pragma unroll
  for (int i = 0; i < 5; ++i) {
    int q = wv * 5 + i;
    int off = q * 1024 + lane * 16;
    const u16* base; u32 eoff; u32 fl = 0;
    if (q < 16) {
      int loc = off & 8191;
      int row = loc >> 7, bir = loc & 127;
      int lb = bir ^ ((row & 7) << 4);
      eoff = (u32)(rb * 64 + row) * HDIM + (u32)(lb >> 1);
      base = (q < 8) ? h2h : h2l;
      fl = 1;
    } else {
      int loc = off - 16384;
      int lo = 0; if (loc >= 12288) { lo = 1; loc -= 12288; }
      int brow = loc >> 7, bir = loc & 127;
      int lb = bir ^ ((brow & 7) << 4);
      int g = brow >> 5, r = brow & 31;
      eoff = (u32)(g * 512 + cb * 32 + r) * HDIM + (u32)(lb >> 1);
      base = lo ? Wh2l : Wh2h;
    }
    shptr[i] = base + eoff; shfl_[i] = fl;
  }

  // ---- LDS read offsets ----
  const u32 swz = (u32)(l15 & 7) << 4;
  const u32 aoff = (u32)(16 * rt + l15) * 128;
  u32 boff[3];
#pragma unroll
  for (int g = 0; g < 3; ++g) boff[g] = (u32)(g * 32 + ch * 16 + l15) * 128;

  const f32x4 vzero = {0.f, 0.f, 0.f, 0.f};
  f32x4 acc1[3] = {vzero, vzero, vzero};
  float h1s[4] = {0.f, 0.f, 0.f, 0.f}, h2s[4] = {0.f, 0.f, 0.f, 0.f};

  gbar_wait(bar + 1024, 1);

#define GA_ISSUE(c, curb) do { \
    char* ldsb = smem + (((c) & 1) * PAR); \
    _Pragma("unroll") \
    for (int i_ = 0; i_ < 8; ++i_) { \
      const u16* gp = saptr[i_] + safl[i_] * (u32)(curb) * HPL + (c) * 64; \
      gload16(gp, ldsb + (wv * 8 + i_) * 1024); \
    } \
  } while (0)

#define GH_ISSUE(c, prvb) do { \
    char* ldsb = smem + (((c) & 1) * PAR); \
    _Pragma("unroll") \
    for (int i_ = 0; i_ < 5; ++i_) { \
      const u16* gp = shptr[i_] + shfl_[i_] * (u32)(prvb) * HPL + (c) * 64; \
      gload16(gp, ldsb + (wv * 5 + i_) * 1024); \
    } \
  } while (0)

#define GA_CHUNK(p) do { \
    const char* sm_ = smem + (p) * PAR; \
    _Pragma("unroll") \
    for (int kk = 0; kk < 2; ++kk) { \
      u32 kb = ((u32)(kk * 64) + (u32)(l4 * 16)) ^ swz; \
      bf16x8 ah = *(const bf16x8*)(sm_ + aoff + kb); \
      bf16x8 al = *(const bf16x8*)(sm_ + 8192 + aoff + kb); \
      _Pragma("unroll") \
      for (int g = 0; g < 3; ++g) { \
        bf16x8 bih = *(const bf16x8*)(sm_ + 16384 + boff[g] + kb); \
        bf16x8 buh = *(const bf16x8*)(sm_ + 28672 + boff[g] + kb); \
        bf16x8 bil = *(const bf16x8*)(sm_ + 40960 + boff[g] + kb); \
        bf16x8 bul = *(const bf16x8*)(sm_ + 53248 + boff[g] + kb); \
        acci[g] = MFMA(ah, bih, acci[g]); \
        acci[g] = MFMA(al, bih, acci[g]); \
        acci[g] = MFMA(ah, bil, acci[g]); \
        acn[g] = MFMA(ah, buh, acn[g]); \
        acn[g] = MFMA(al, buh, acn[g]); \
        acn[g] = MFMA(ah, bul, acn[g]); \
      } \
    } \
  } while (0)

#define GH_CHUNK(p) do { \
    const char* sm_ = smem + (p) * PAR; \
    _Pragma("unroll") \
    for (int kk = 0; kk < 2; ++kk) { \
      u32 kb = ((u32)(kk * 64) + (u32)(l4 * 16)) ^ swz; \
      bf16x8 ah = *(const bf16x8*)(sm_ + aoff + kb); \
      bf16x8 al = *(const bf16x8*)(sm_ + 8192 + aoff + kb); \
      _Pragma("unroll") \
      for (int g = 0; g < 3; ++g) { \
        bf16x8 bh = *(const bf16x8*)(sm_ + 16384 + boff[g] + kb); \
        bf16x8 bl = *(const bf16x8*)(sm_ + 28672 + boff[g] + kb); \
        acch[g] = MFMA(ah, bh, acch[g]); \
        acch[g] = MFMA(al, bh, acch[g]); \
        acch[g] = MFMA(ah, bl, acch[g]); \
      } \
    } \
  } while (0)

  for (int t = 0; t < TSTEPS; ++t) {
    const int cur = t & 1, prv = cur ^ 1;

    // prefetch teacher-forced input before the barrier wait
    float xpre[4];
    if (t < WUP) {
#pragma unroll
      for (int rr = 0; rr < 4; ++rr)
        xpre[rr] = input[(rb * 64 + 16 * rt + l4 * 4 + rr) * 1024 + t];
    }

    if (t > 0) g_wait(gb2, t);   // h2(t-1), out(t-1) visible

    if (cb == 0 && tid < 64) {
      int b = rb * 64 + tid;
      if (t > 0) dout[b * 1024 + (t - 1)] = outsc[prv * 1024 + b] + blin;
      outsc[cur * 1024 + b] = 0.f;   // zero accumulator for this step
    }

    // ---- elementwise 1: h1(t) ----
    {
      u16* h1hc = h1h + cur * HPL;
      u16* h1lc = h1l + cur * HPL;
#pragma unroll
      for (int rr = 0; rr < 4; ++rr) {
        int b = rb * 64 + 16 * rt + l4 * 4 + rr;
        float x = (t < WUP) ? xpre[rr] : (outsc[prv * 1024 + b] + blin);
        float r = sigm(fmaf(x, wi_r, bi_r) + acc1[0][rr] + bh_r);
        float z = sigm(fmaf(x, wi_z, bi_z) + acc1[1][rr] + bh_z);
        float n = tanh_(fmaf(r, acc1[2][rr] + bh_n, fmaf(x, wi_n, bi_n)));
        float h = (1.f - z) * n + z * h1s[rr];
        h1s[rr] = h;
        u16 hbv = f2bf(h);
        int idx = b * HDIM + j;
        h1hc[idx] = hbv; h1lc[idx] = f2bf(h - bf2f(hbv));
      }
    }
    g_arrive(gb1, t + 1);   // publish h1(t)

    // ---- G_H: gh2 = h2(t-1)@Whh2^T (hides B1 latency) ----
    f32x4 acch[3] = {vzero, vzero, vzero};
    if (t > 0) {
      GH_ISSUE(0, prv);
      for (int c = 0; c < 8; ++c) {
        if (c < 7) {
          __builtin_amdgcn_s_barrier();
          GH_ISSUE(c + 1, prv);
          asm volatile("s_waitcnt vmcnt(5)" ::: "memory");
        } else {
          asm volatile("s_waitcnt vmcnt(0)" ::: "memory");
        }
        __builtin_amdgcn_s_barrier();
        GH_CHUNK(c & 1);
      }
    }
    g_wait(gb1, t + 1);

    // ---- G_A: gi2(t) + gh1(t+1) from h1(t) ----
    f32x4 acci[3] = {vzero, vzero, vzero};
    f32x4 acn[3] = {vzero, vzero, vzero};
    {
      GA_ISSUE(0, cur);
      for (int c = 0; c < 8; ++c) {
        if (c < 7) {
          __builtin_amdgcn_s_barrier();
          GA_ISSUE(c + 1, cur);
          asm volatile("s_waitcnt vmcnt(8)" ::: "memory");
        } else {
          asm volatile("s_waitcnt vmcnt(0)" ::: "memory");
        }
        __builtin_amdgcn_s_barrier();
        GA_CHUNK(c & 1);
      }
    }

    // ---- elementwise 2: h2(t) + output matvec ----
    {
      u16* h2hc = h2h + cur * HPL;
      u16* h2lc = h2l + cur * HPL;
#pragma unroll
      for (int rr = 0; rr < 4; ++rr) {
        int b = rb * 64 + 16 * rt + l4 * 4 + rr;
        float r = sigm(acci[0][rr] + c2i_r + acch[0][rr] + c2h_r);
        float z = sigm(acci[1][rr] + c2i_z + acch[1][rr] + c2h_z);
        float n = tanh_(fmaf(r, acch[2][rr] + c2h_n, acci[2][rr] + c2i_n));
        float h = (1.f - z) * n + z * h2s[rr];
        h2s[rr] = h;
        u16 hbv = f2bf(h);
        int idx = b * HDIM + j;
        h2hc[idx] = hbv; h2lc[idx] = f2bf(h - bf2f(hbv));
        float v = h * wlj;
        v += __shfl_xor(v, 1);
        v += __shfl_xor(v, 2);
        v += __shfl_xor(v, 4);
        v += __shfl_xor(v, 8);
        if (l15 == 0) atomicAdd(outsc + cur * 1024 + b, v);
      }
    }
#pragma unroll
    for (int g = 0; g < 3; ++g) acc1[g] = acn[g];

    g_arrive(gb2, t + 1);   // publish h2(t) + out(t)
  }

  g_wait(gb2, TSTEPS);
  if (cb == 0 && tid < 64) {
    int b = rb * 64 + tid;
    dout[b * 1024 + 1023] = outsc[1024 + b] + blin;
  }
}

extern "C" void kernel_launch(void* const* d_in, const int* in_sizes, int n_in,
                              void* d_out, int out_size, void* d_ws, size_t ws_size,
                              hipStream_t stream) {
  (void)in_sizes; (void)n_in; (void)out_size; (void)ws_size;
  const float* input = (const float*)d_in[0];
  const float* Wih1  = (const float*)d_in[1];
  const float* Whh1  = (const float*)d_in[2];
  const float* bih1  = (const float*)d_in[3];
  const float* bhh1  = (const float*)d_in[4];
  const float* Wih2  = (const float*)d_in[5];
  const float* Whh2  = (const float*)d_in[6];
  const float* bih2  = (const float*)d_in[7];
  const float* bhh2  = (const float*)d_in[8];
  const float* Wlin  = (const float*)d_in[9];
  const float* blin  = (const float*)d_in[10];

  u16* wsp = (u16*)d_ws;
  size_t u16_count = (size_t)6 * WPL + (size_t)8 * HPL;
  float* outsc = (float*)((char*)d_ws + u16_count * 2);
  int* bar = (int*)((char*)outsc + 2048 * sizeof(float));

  hipMemsetAsync(bar, 0, 3 * 1024 * sizeof(int), stream);
  gru_seq_kernel<<<NBLK, NTHR, 0, stream>>>(input, Wih1, Whh1, bih1, bhh1,
                                            Wih2, Whh2, bih2, bhh2, Wlin, blin,
                                            (float*)d_out, wsp, outsc, bar);
}

// Round 4
// 43335.825 us; speedup vs baseline: 1.2768x; 1.2768x over previous
//
#include <hip/hip_runtime.h>

#define NBLK 256
#define NTHR 512
#define HDIM 512
#define TSTEPS 1024
#define WUP 512
#define WPL 786432   /* weight plane elems: 1536*512 */
#define HPL 524288   /* h plane elems per buffer: 1024*512 */
#define PAR 65536    /* LDS parity stride */

typedef unsigned short u16;
typedef unsigned int u32;
typedef __bf16 bf16x8 __attribute__((ext_vector_type(8)));
typedef float f32x4 __attribute__((ext_vector_type(4)));
typedef int i32x4 __attribute__((ext_vector_type(4)));

typedef __attribute__((address_space(3))) void as3v;
typedef __attribute__((address_space(1))) const void as1cv;

__device__ __forceinline__ void gload16(const u16* g, char* l) {
  __builtin_amdgcn_global_load_lds((as1cv*)g, (as3v*)l, 16, 0, 0);
}
// coherent (L1/L2-bypass) 16B load: reads at the L3 coherence point, no cache inv
__device__ __forceinline__ i32x4 load_sc(const u16* p) {
  i32x4 r;
  asm volatile("global_load_dwordx4 %0, %1, off sc0 sc1" : "=v"(r) : "v"(p) : "memory");
  return r;
}

__device__ __forceinline__ u16 f2bf(float f) {
  u32 u = __float_as_uint(f);
  u += 0x7fffu + ((u >> 16) & 1u);   // RNE to bf16
  return (u16)(u >> 16);
}
__device__ __forceinline__ float bf2f(u16 s) { return __uint_as_float(((u32)s) << 16); }
__device__ __forceinline__ float sigm(float v) { return 1.f / (1.f + __expf(-v)); }
__device__ __forceinline__ float tanh_(float v) {
  float e = __expf(2.f * v);
  return 1.f - 2.f / (e + 1.f);
}
__device__ __forceinline__ f32x4 MFMA(bf16x8 a, bf16x8 b, f32x4 c) {
  return __builtin_amdgcn_mfma_f32_16x16x32_bf16(a, b, c, 0, 0, 0);
}

// ---- group barrier: monotonic counter gb[0], flag gb[32]; NO acquire-inv ----
// arrive: RELEASE RMW (emits wbl2 writeback only -> L2 stays valid).
// wait: RELAXED polls (read at L3, no invalidation). Cross-block data is read
// with sc0/sc1 coherent loads, so no acquire fence is needed at agent scope.
__device__ __forceinline__ void g_arrive(int* gb) {
  __syncthreads();
  if (threadIdx.x == 0) {
    int old = __hip_atomic_fetch_add(gb, 1, __ATOMIC_RELEASE, __HIP_MEMORY_SCOPE_AGENT);
    if ((old & 15) == 15)
      __hip_atomic_fetch_add(gb + 32, 1, __ATOMIC_RELEASE, __HIP_MEMORY_SCOPE_AGENT);
  }
}
__device__ __forceinline__ void g_wait(int* gb, int target) {
  if (threadIdx.x == 0) {
    while (__hip_atomic_load(gb + 32, __ATOMIC_RELAXED, __HIP_MEMORY_SCOPE_AGENT) < target)
      __builtin_amdgcn_s_sleep(1);
  }
  __builtin_amdgcn_fence(__ATOMIC_ACQUIRE, "workgroup");  // compiler/L1-level ordering only
  __syncthreads();
}

__global__ __launch_bounds__(NTHR, 2) void gru_seq_kernel(
    const float* __restrict__ input, const float* __restrict__ Wih1,
    const float* __restrict__ Whh1, const float* __restrict__ bih1, const float* __restrict__ bhh1,
    const float* __restrict__ Wih2, const float* __restrict__ Whh2,
    const float* __restrict__ bih2, const float* __restrict__ bhh2,
    const float* __restrict__ Wlin, const float* __restrict__ blinp,
    float* __restrict__ dout, u16* __restrict__ wsp, float* __restrict__ outsc,
    int* __restrict__ bar) {
  __shared__ __align__(16) char smem[131072];
  const int wg = blockIdx.x, tid = threadIdx.x;
  const int lane = tid & 63, wv = tid >> 6;
  const int l15 = lane & 15, l4 = lane >> 4;
  const int rt = wv >> 1, ch = wv & 1;

  u16* Wh1h = wsp;           u16* Wh1l = wsp + WPL;
  u16* Wi2h = wsp + 2 * WPL; u16* Wi2l = wsp + 3 * WPL;
  u16* Wh2h = wsp + 4 * WPL; u16* Wh2l = wsp + 5 * WPL;
  u16* hb_  = wsp + 6 * WPL;
  u16* h1h = hb_;            u16* h1l = hb_ + 2 * HPL;   // [2][HPL] each
  u16* h2h = hb_ + 4 * HPL;  u16* h2l = hb_ + 6 * HPL;
  int* ibar = bar + 2048;

  // ---- init: split weights into bf16 hi/lo planes (pre-swizzled row layout) ----
  for (int i = wg * NTHR + tid; i < 3 * WPL; i += NBLK * NTHR) {
    int m = i / WPL, r = i - m * WPL;
    const float* src = (m == 0) ? Whh1 : (m == 1) ? Wih2 : Whh2;
    u16* dh = (m == 0) ? Wh1h : (m == 1) ? Wi2h : Wh2h;
    u16* dl = (m == 0) ? Wh1l : (m == 1) ? Wi2l : Wh2l;
    float v = src[r];
    u16 hbv = f2bf(v);
    dh[r] = hbv; dl[r] = f2bf(v - bf2f(hbv));
  }
  __syncthreads();
  if (tid == 0) {
    int old = __hip_atomic_fetch_add(ibar, 1, __ATOMIC_RELEASE, __HIP_MEMORY_SCOPE_AGENT);
    if (old == NBLK - 1)
      __hip_atomic_fetch_add(ibar + 32, 1, __ATOMIC_RELEASE, __HIP_MEMORY_SCOPE_AGENT);
  }

  // ---- block decomposition: xcd = wg&7 hosts col-slabs {2x,2x+1} (weights L2-resident) ----
  const int xm = wg >> 3;
  const int cb = (wg & 7) * 2 + (xm & 1);   // 0..15 column-block (32 hcols)
  const int rb = xm >> 1;                   // 0..15 row-block (64 batch rows)
  int* gb1 = bar + rb * 128;
  int* gb2 = bar + rb * 128 + 64;

  // ---- per-lane constants ----
  const int j = cb * 32 + ch * 16 + l15;
  const float blin = blinp[0];
  const float wi_r = Wih1[j], wi_z = Wih1[j + 512], wi_n = Wih1[j + 1024];
  const float bi_r = bih1[j], bi_z = bih1[j + 512], bi_n = bih1[j + 1024];
  const float bh_r = bhh1[j], bh_z = bhh1[j + 512], bh_n = bhh1[j + 1024];
  const float c2i_r = bih2[j], c2i_z = bih2[j + 512], c2i_n = bih2[j + 1024];
  const float c2h_r = bhh2[j], c2h_z = bhh2[j + 512], c2h_n = bhh2[j + 1024];
  const float wlj = Wlin[j];

  // ---- weight staging slots (global_load_lds, L2-cached) ----
  // G_A B region: LDS [16384,65536): Bh 24K (Wih2 rows0-95 | Whh1 rows96-191), Bl 24K
  const u16* wptrA[6]; int wdstA[6];
#pragma unroll
  for (int i = 0; i < 6; ++i) {
    int off = 16384 + (wv * 6 + i) * 1024 + lane * 16;
    int loc = off - 16384;
    int lo = 0; if (loc >= 24576) { lo = 1; loc -= 24576; }
    int brow = loc >> 7, bir = loc & 127;
    int lb = bir ^ ((brow & 7) << 4);
    int mat = (brow >= 96) ? 1 : 0;
    int s = brow - 96 * mat;
    int g = s >> 5, r = s & 31;
    u32 eoff = (u32)(g * 512 + cb * 32 + r) * HDIM + (u32)(lb >> 1);
    wptrA[i] = (mat ? (lo ? Wh1l : Wh1h) : (lo ? Wi2l : Wi2h)) + eoff;
    wdstA[i] = 16384 + (wv * 6 + i) * 1024;
  }
  // G_H B region: LDS [16384,40960): Bh 12K (Whh2), Bl 12K
  const u16* wptrH[3]; int wdstH[3];
#pragma unroll
  for (int i = 0; i < 3; ++i) {
    int off = 16384 + (wv * 3 + i) * 1024 + lane * 16;
    int loc = off - 16384;
    int lo = 0; if (loc >= 12288) { lo = 1; loc -= 12288; }
    int brow = loc >> 7, bir = loc & 127;
    int lb = bir ^ ((brow & 7) << 4);
    int g = brow >> 5, r = brow & 31;
    u32 eoff = (u32)(g * 512 + cb * 32 + r) * HDIM + (u32)(lb >> 1);
    wptrH[i] = (lo ? Wh2l : Wh2h) + eoff;
    wdstH[i] = 16384 + (wv * 3 + i) * 1024;
  }

  // ---- A (h) reg-staging geometry: 2 pieces/lane/chunk (hi,lo), swizzle at ds_write ----
  const int r_ = tid >> 3, kb_ = (tid & 7) * 16;
  const u32 rowel = (u32)(rb * 64 + r_) * HDIM + (u32)(kb_ >> 1);
  const u32 ldsAh = (u32)(r_ << 7) + (u32)(kb_ ^ ((r_ & 7) << 4));
  const u32 ldsAl = 8192 + ldsAh;

  // ---- LDS read offsets (unchanged) ----
  const u32 swz = (u32)(l15 & 7) << 4;
  const u32 aoff = (u32)(16 * rt + l15) * 128;
  u32 boff[3];
#pragma unroll
  for (int g = 0; g < 3; ++g) boff[g] = (u32)(g * 32 + ch * 16 + l15) * 128;

  const f32x4 vzero = {0.f, 0.f, 0.f, 0.f};
  f32x4 acc1[3] = {vzero, vzero, vzero};
  float h1s[4] = {0.f, 0.f, 0.f, 0.f}, h2s[4] = {0.f, 0.f, 0.f, 0.f};

  // wait init done (relaxed poll; consumers first-touch weight lines after this)
  if (tid == 0) {
    while (__hip_atomic_load(ibar + 32, __ATOMIC_RELAXED, __HIP_MEMORY_SCOPE_AGENT) < 1)
      __builtin_amdgcn_s_sleep(1);
  }
  __builtin_amdgcn_fence(__ATOMIC_ACQUIRE, "workgroup");
  __syncthreads();

#define GA_CHUNK(p) do { \
    const char* sm_ = smem + (p) * PAR; \
    _Pragma("unroll") \
    for (int kk = 0; kk < 2; ++kk) { \
      u32 kb = ((u32)(kk * 64) + (u32)(l4 * 16)) ^ swz; \
      bf16x8 ah = *(const bf16x8*)(sm_ + aoff + kb); \
      bf16x8 al = *(const bf16x8*)(sm_ + 8192 + aoff + kb); \
      _Pragma("unroll") \
      for (int g = 0; g < 3; ++g) { \
        bf16x8 bih = *(const bf16x8*)(sm_ + 16384 + boff[g] + kb); \
        bf16x8 buh = *(const bf16x8*)(sm_ + 28672 + boff[g] + kb); \
        bf16x8 bil = *(const bf16x8*)(sm_ + 40960 + boff[g] + kb); \
        bf16x8 bul = *(const bf16x8*)(sm_ + 53248 + boff[g] + kb); \
        acci[g] = MFMA(ah, bih, acci[g]); \
        acci[g] = MFMA(al, bih, acci[g]); \
        acci[g] = MFMA(ah, bil, acci[g]); \
        acn[g] = MFMA(ah, buh, acn[g]); \
        acn[g] = MFMA(al, buh, acn[g]); \
        acn[g] = MFMA(ah, bul, acn[g]); \
      } \
    } \
  } while (0)

#define GH_CHUNK(p) do { \
    const char* sm_ = smem + (p) * PAR; \
    _Pragma("unroll") \
    for (int kk = 0; kk < 2; ++kk) { \
      u32 kb = ((u32)(kk * 64) + (u32)(l4 * 16)) ^ swz; \
      bf16x8 ah = *(const bf16x8*)(sm_ + aoff + kb); \
      bf16x8 al = *(const bf16x8*)(sm_ + 8192 + aoff + kb); \
      _Pragma("unroll") \
      for (int g = 0; g < 3; ++g) { \
        bf16x8 bh = *(const bf16x8*)(sm_ + 16384 + boff[g] + kb); \
        bf16x8 bl = *(const bf16x8*)(sm_ + 28672 + boff[g] + kb); \
        acch[g] = MFMA(ah, bh, acch[g]); \
        acch[g] = MFMA(al, bh, acch[g]); \
        acch[g] = MFMA(ah, bl, acch[g]); \
      } \
    } \
  } while (0)

  for (int t = 0; t < TSTEPS; ++t) {
    const int cur = t & 1, prv = cur ^ 1;

    // prefetch teacher-forced input before the barrier wait (plain load, read-only)
    float xpre[4];
    if (t < WUP) {
#pragma unroll
      for (int rr = 0; rr < 4; ++rr)
        xpre[rr] = input[(rb * 64 + 16 * rt + l4 * 4 + rr) * 1024 + t];
    }

    if (t > 0) g_wait(gb2, t);   // h2(t-1), out(t-1) published

    if (cb == 0 && tid < 64) {
      int b = rb * 64 + tid;
      if (t > 0) {
        float osc = __hip_atomic_load(outsc + prv * 1024 + b, __ATOMIC_RELAXED,
                                      __HIP_MEMORY_SCOPE_AGENT);
        dout[b * 1024 + (t - 1)] = osc + blin;
      }
      outsc[cur * 1024 + b] = 0.f;   // plain store; wb'd by bar1-arrive release
    }

    // ---- elementwise 1: h1(t) ----
    {
      u16* h1hc = h1h + cur * HPL;
      u16* h1lc = h1l + cur * HPL;
#pragma unroll
      for (int rr = 0; rr < 4; ++rr) {
        int b = rb * 64 + 16 * rt + l4 * 4 + rr;
        float x;
        if (t < WUP) {
          x = xpre[rr];
        } else {
          x = __hip_atomic_load(outsc + prv * 1024 + b, __ATOMIC_RELAXED,
                                __HIP_MEMORY_SCOPE_AGENT) + blin;
        }
        float r = sigm(fmaf(x, wi_r, bi_r) + acc1[0][rr] + bh_r);
        float z = sigm(fmaf(x, wi_z, bi_z) + acc1[1][rr] + bh_z);
        float n = tanh_(fmaf(r, acc1[2][rr] + bh_n, fmaf(x, wi_n, bi_n)));
        float h = (1.f - z) * n + z * h1s[rr];
        h1s[rr] = h;
        u16 hbv = f2bf(h);
        int idx = b * HDIM + j;
        h1hc[idx] = hbv; h1lc[idx] = f2bf(h - bf2f(hbv));
      }
    }
    g_arrive(gb1);   // publish h1(t): release-RMW -> wbl2 (writeback, no inv)

    // ---- G_H: gh2 = h2(t-1)@Whh2^T (overlaps bar1 latency) ----
    f32x4 acch[3] = {vzero, vzero, vzero};
    if (t > 0) {
      const u16* pAh = h2h + prv * HPL + rowel;
      const u16* pAl = h2l + prv * HPL + rowel;
      i32x4 rh[2], rl[2];
      rh[0] = load_sc(pAh);
      rl[0] = load_sc(pAl);
#pragma unroll
      for (int i = 0; i < 3; ++i) gload16(wptrH[i], smem + wdstH[i]);
#pragma unroll
      for (int c = 0; c < 8; ++c) {
        char* bufc = smem + (c & 1) * PAR;
        asm volatile("s_waitcnt vmcnt(3)" ::: "memory");   // h(c) regs arrived
        *(i32x4*)(bufc + ldsAh) = rh[c & 1];
        *(i32x4*)(bufc + ldsAl) = rl[c & 1];
        if (c < 7) {
          rh[(c + 1) & 1] = load_sc(pAh + (c + 1) * 64);
          rl[(c + 1) & 1] = load_sc(pAl + (c + 1) * 64);
          char* bufn = smem + ((c + 1) & 1) * PAR;
#pragma unroll
          for (int i = 0; i < 3; ++i) gload16(wptrH[i] + (c + 1) * 64, bufn + wdstH[i]);
          asm volatile("s_waitcnt vmcnt(5)" ::: "memory"); // W(c) landed in LDS
        } else {
          asm volatile("s_waitcnt vmcnt(0)" ::: "memory");
        }
        asm volatile("s_waitcnt lgkmcnt(0)" ::: "memory"); // my ds_writes done
        __builtin_amdgcn_s_barrier();
        GH_CHUNK(c & 1);
        __builtin_amdgcn_s_barrier();
      }
    }
    g_wait(gb1, t + 1);

    // ---- G_A: gi2(t) + gh1(t+1) from h1(t) ----
    f32x4 acci[3] = {vzero, vzero, vzero};
    f32x4 acn[3] = {vzero, vzero, vzero};
    {
      const u16* pAh = h1h + cur * HPL + rowel;
      const u16* pAl = h1l + cur * HPL + rowel;
      i32x4 rh[2], rl[2];
      rh[0] = load_sc(pAh);
      rl[0] = load_sc(pAl);
#pragma unroll
      for (int i = 0; i < 6; ++i) gload16(wptrA[i], smem + wdstA[i]);
#pragma unroll
      for (int c = 0; c < 8; ++c) {
        char* bufc = smem + (c & 1) * PAR;
        asm volatile("s_waitcnt vmcnt(6)" ::: "memory");
        *(i32x4*)(bufc + ldsAh) = rh[c & 1];
        *(i32x4*)(bufc + ldsAl) = rl[c & 1];
        if (c < 7) {
          rh[(c + 1) & 1] = load_sc(pAh + (c + 1) * 64);
          rl[(c + 1) & 1] = load_sc(pAl + (c + 1) * 64);
          char* bufn = smem + ((c + 1) & 1) * PAR;
#pragma unroll
          for (int i = 0; i < 6; ++i) gload16(wptrA[i] + (c + 1) * 64, bufn + wdstA[i]);
          asm volatile("s_waitcnt vmcnt(8)" ::: "memory");
        } else {
          asm volatile("s_waitcnt vmcnt(0)" ::: "memory");
        }
        asm volatile("s_waitcnt lgkmcnt(0)" ::: "memory");
        __builtin_amdgcn_s_barrier();
        GA_CHUNK(c & 1);
        __builtin_amdgcn_s_barrier();
      }
    }

    // ---- elementwise 2: h2(t) + output matvec ----
    {
      u16* h2hc = h2h + cur * HPL;
      u16* h2lc = h2l + cur * HPL;
#pragma unroll
      for (int rr = 0; rr < 4; ++rr) {
        int b = rb * 64 + 16 * rt + l4 * 4 + rr;
        float r = sigm(acci[0][rr] + c2i_r + acch[0][rr] + c2h_r);
        float z = sigm(acci[1][rr] + c2i_z + acch[1][rr] + c2h_z);
        float n = tanh_(fmaf(r, acch[2][rr] + c2h_n, acci[2][rr] + c2i_n));
        float h = (1.f - z) * n + z * h2s[rr];
        h2s[rr] = h;
        u16 hbv = f2bf(h);
        int idx = b * HDIM + j;
        h2hc[idx] = hbv; h2lc[idx] = f2bf(h - bf2f(hbv));
        float v = h * wlj;
        v += __shfl_xor(v, 1);
        v += __shfl_xor(v, 2);
        v += __shfl_xor(v, 4);
        v += __shfl_xor(v, 8);
        if (l15 == 0) atomicAdd(outsc + cur * 1024 + b, v);
      }
    }
#pragma unroll
    for (int g = 0; g < 3; ++g) acc1[g] = acn[g];

    g_arrive(gb2);   // publish h2(t) + out(t)
  }

  g_wait(gb2, TSTEPS);
  if (cb == 0 && tid < 64) {
    int b = rb * 64 + tid;
    float osc = __hip_atomic_load(outsc + 1024 + b, __ATOMIC_RELAXED,
                                  __HIP_MEMORY_SCOPE_AGENT);
    dout[b * 1024 + 1023] = osc + blin;
  }
}

extern "C" void kernel_launch(void* const* d_in, const int* in_sizes, int n_in,
                              void* d_out, int out_size, void* d_ws, size_t ws_size,
                              hipStream_t stream) {
  (void)in_sizes; (void)n_in; (void)out_size; (void)ws_size;
  const float* input = (const float*)d_in[0];
  const float* Wih1  = (const float*)d_in[1];
  const float* Whh1  = (const float*)d_in[2];
  const float* bih1  = (const float*)d_in[3];
  const float* bhh1  = (const float*)d_in[4];
  const float* Wih2  = (const float*)d_in[5];
  const float* Whh2  = (const float*)d_in[6];
  const float* bih2  = (const float*)d_in[7];
  const float* bhh2  = (const float*)d_in[8];
  const float* Wlin  = (const float*)d_in[9];
  const float* blin  = (const float*)d_in[10];

  u16* wsp = (u16*)d_ws;
  size_t u16_count = (size_t)6 * WPL + (size_t)8 * HPL;
  float* outsc = (float*)((char*)d_ws + u16_count * 2);
  int* bar = (int*)((char*)outsc + 2048 * sizeof(float));

  hipMemsetAsync(bar, 0, 3 * 1024 * sizeof(int), stream);
  gru_seq_kernel<<<NBLK, NTHR, 0, stream>>>(input, Wih1, Whh1, bih1, bhh1,
                                            Wih2, Whh2, bih2, bhh2, Wlin, blin,
                                            (float*)d_out, wsp, outsc, bar);
}